// Round 7
// baseline (695.364 us; speedup 1.0000x reference)
//
#include <hip/hip_runtime.h>
#include <cstddef>

// Problem constants
#define B_ 128
#define H_ 1024
#define S_ 512

// ======================================================================
// Shared skinny-GEMM tile machinery: M=128 (all batch), BN=16, KC=64.
// A staged transposed+XOR-swizzled in LDS: As[k][b ^ xc(k)] = A[b][k0+k],
// xc(k) = ((k>>2)&7)<<2  -> conflict-free b128 on both store and load.
// W staged as Ws[n][k] (16x68, pad for banks).
// Thread (tb=tid&31, tn=tid>>5) computes 4 consecutive b x 2 n outputs.
// ======================================================================

__device__ __forceinline__ void stage_A128(float* As, const float* __restrict__ A, int k0, int tid){
  int c4 = tid & 15, rowg = tid >> 4;
#pragma unroll
  for (int p = 0; p < 8; ++p){
    int row = p*16 + rowg;
    const float4 v = *reinterpret_cast<const float4*>(A + (size_t)row*H_ + k0 + c4*4);
    int colx = row ^ ((c4 & 7) << 2);
    float* d0 = As + (c4*4)*132 + colx;
    d0[0]     = v.x;
    d0[132]   = v.y;
    d0[264]   = v.z;
    d0[396]   = v.w;
  }
}

// W row-major [N][ldw] (weight rows = output features, contiguous K)
__device__ __forceinline__ void stage_W_wt(float* Ws, const float* __restrict__ W, int n0, int k0, int ldw, int tid){
  int n = tid >> 4, c4 = tid & 15;
  const float4 v = *reinterpret_cast<const float4*>(W + (size_t)(n0+n)*ldw + k0 + c4*4);
  *reinterpret_cast<float4*>(Ws + n*68 + c4*4) = v;
}

// W k-major [K][ldw] (q = rnn @ W_attn case): Ws[n][k] = W[k0+k][n0+n]
__device__ __forceinline__ void stage_W_wn(float* Ws, const float* __restrict__ W, int n0, int k0, int ldw, int tid){
  int k = tid >> 2, c4 = tid & 3;
  const float4 v = *reinterpret_cast<const float4*>(W + (size_t)(k0+k)*ldw + n0 + c4*4);
  Ws[(c4*4+0)*68 + k] = v.x;
  Ws[(c4*4+1)*68 + k] = v.y;
  Ws[(c4*4+2)*68 + k] = v.z;
  Ws[(c4*4+3)*68 + k] = v.w;
}

__device__ __forceinline__ void compute_chunk(const float* As, const float* Ws, int tb, int tn, float acc[4][2]){
#pragma unroll
  for (int kk = 0; kk < 64; kk += 4){
    int col = (4*tb) ^ (((kk >> 2) & 7) << 2);
    float av[4][4];
#pragma unroll
    for (int k = 0; k < 4; ++k)
      *reinterpret_cast<float4*>(av[k]) = *reinterpret_cast<const float4*>(As + (kk+k)*132 + col);
    float w0[4], w1[4];
    *reinterpret_cast<float4*>(w0) = *reinterpret_cast<const float4*>(Ws + (tn*2+0)*68 + kk);
    *reinterpret_cast<float4*>(w1) = *reinterpret_cast<const float4*>(Ws + (tn*2+1)*68 + kk);
#pragma unroll
    for (int k = 0; k < 4; ++k){
#pragma unroll
      for (int i = 0; i < 4; ++i){
        acc[i][0] = fmaf(av[k][i], w0[k], acc[i][0]);
        acc[i][1] = fmaf(av[k][i], w1[k], acc[i][1]);
      }
    }
  }
}

// ---------------- K1: fused gi|gh GEMM -> G[128][6144] ----------------
// cols 0..3071 = input_seq @ W_ih^T + b_ih ; 3072..6143 = h @ W_hh^T + b_hh
__global__ __launch_bounds__(256) void gru_gemm(const float* __restrict__ Ain, const float* __restrict__ Ah,
                                                const float* __restrict__ Wih, const float* __restrict__ Whh,
                                                const float* __restrict__ bih, const float* __restrict__ bhh,
                                                float* __restrict__ G){
  __shared__ float As[64*132];
  __shared__ float Ws[16*68];
  int tid = threadIdx.x;
  int n0g = blockIdx.x * 16;
  const float* A; const float* W; const float* bias; int n0;
  if (n0g < 3072){ A = Ain; W = Wih; bias = bih; n0 = n0g; }
  else           { A = Ah;  W = Whh; bias = bhh; n0 = n0g - 3072; }
  int tb = tid & 31, tn = tid >> 5;
  float acc[4][2] = {{0.f,0.f},{0.f,0.f},{0.f,0.f},{0.f,0.f}};
  for (int k0 = 0; k0 < H_; k0 += 64){
    __syncthreads();
    stage_A128(As, A, k0, tid);
    stage_W_wt(Ws, W, n0, k0, H_, tid);
    __syncthreads();
    compute_chunk(As, Ws, tb, tn, acc);
  }
#pragma unroll
  for (int i = 0; i < 4; ++i){
    int b = tb*4 + i;
#pragma unroll
    for (int j = 0; j < 2; ++j){
      int n = tn*2 + j;
      G[(size_t)b*6144 + n0g + n] = acc[i][j] + bias[n0 + n];
    }
  }
}

// ---------------- generic skinny GEMM (K3 q, K7 concat, K8 out) -------
template<int KDIM, bool WT, int ACT, bool ASPLIT>
__global__ __launch_bounds__(256) void gemm_tile(const float* __restrict__ A1, const float* __restrict__ A2,
                                                 const float* __restrict__ W, const float* __restrict__ bias,
                                                 float* __restrict__ C){
  __shared__ float As[64*132];
  __shared__ float Ws[16*68];
  int tid = threadIdx.x;
  int n0 = blockIdx.x * 16;
  int tb = tid & 31, tn = tid >> 5;
  float acc[4][2] = {{0.f,0.f},{0.f,0.f},{0.f,0.f},{0.f,0.f}};
  for (int k0 = 0; k0 < KDIM; k0 += 64){
    const float* A = A1; int keff = k0;
    if (ASPLIT && k0 >= 1024){ A = A2; keff = k0 - 1024; }
    __syncthreads();
    stage_A128(As, A, keff, tid);
    if (WT) stage_W_wt(Ws, W, n0, k0, KDIM, tid);
    else    stage_W_wn(Ws, W, n0, k0, 1024, tid);
    __syncthreads();
    compute_chunk(As, Ws, tb, tn, acc);
  }
#pragma unroll
  for (int i = 0; i < 4; ++i){
    int b = tb*4 + i;
#pragma unroll
    for (int j = 0; j < 2; ++j){
      int n = tn*2 + j;
      float v = acc[i][j] + (bias ? bias[n0 + n] : 0.f);
      if (ACT == 1) v = tanhf(v);
      if (ACT == 2) v = 1.f/(1.f + expf(-v));
      C[(size_t)b*1024 + n0 + n] = v;
    }
  }
}

// ---------------- K2: GRU gates -> rnn_output, hidden out, t[b] -------
// One block per batch row b (1024 threads). Also computes t[b]=rnn[b].b_attn
// (fused to avoid a separate tiny launch in the serial chain).
__global__ __launch_bounds__(1024) void gru_gates(const float* __restrict__ G, const float* __restrict__ h,
                                                  const float* __restrict__ ba,
                                                  float* __restrict__ rnn, float* __restrict__ hid_out,
                                                  float* __restrict__ t){
  int b = blockIdx.x, c = threadIdx.x;
  __shared__ float red[16];
  const float* g = G + (size_t)b*6144;
  float ir = g[c],        iz = g[c+1024], in_ = g[c+2048];
  float hr = g[c+3072],   hz = g[c+4096], hn  = g[c+5120];
  float r = 1.f/(1.f + expf(-(ir + hr)));
  float z = 1.f/(1.f + expf(-(iz + hz)));
  float n = tanhf(in_ + r*hn);
  float hv = h[(size_t)b*H_ + c];
  float o = (1.f - z)*n + z*hv;
  rnn[(size_t)b*H_ + c] = o;
  hid_out[(size_t)b*H_ + c] = o;
  // block-reduce o * b_attn[c] -> t[b]
  float s = o * ba[c];
#pragma unroll
  for (int off = 1; off < 64; off <<= 1) s += __shfl_xor(s, off, 64);
  if ((c & 63) == 0) red[c >> 6] = s;
  __syncthreads();
  if (c == 0){
    float acc = 0.f;
#pragma unroll
    for (int j = 0; j < 16; ++j) acc += red[j];
    t[b] = acc;
  }
}

// ---------------- K4: one-pass flash attention over enc ---------------
// grid (128 b, 4 chunk) x 256 thr (4 waves). Wave owns 32 s-rows of one b.
// Per wave: e[b,s] raw stored; partial (m, ctx[1024]) written to ws.
__global__ __launch_bounds__(256) void attn_pass(const float* __restrict__ enc, const float* __restrict__ q,
                                                 const float* __restrict__ t, float* __restrict__ e_out,
                                                 float* __restrict__ ctxp, float* __restrict__ mw){
  int b = blockIdx.x;
  int chunk = blockIdx.y;
  int wave = threadIdx.x >> 6;
  int lane = threadIdx.x & 63;
  int s0 = chunk*128 + wave*32;

  float qv[4][4];
#pragma unroll
  for (int k = 0; k < 4; ++k)
    *reinterpret_cast<float4*>(qv[k]) = *reinterpret_cast<const float4*>(q + (size_t)b*H_ + k*256 + lane*4);
  const float tb = t[b];

  float m = -INFINITY;
  float ctx[4][4] = {{0}};
  const float* rowp = enc + ((size_t)s0 * B_ + b) * H_;
  float rv[4][4];
#pragma unroll
  for (int k = 0; k < 4; ++k)
    *reinterpret_cast<float4*>(rv[k]) = *reinterpret_cast<const float4*>(rowp + k*256 + lane*4);

  for (int i = 0; i < 32; ++i){
    float nv[4][4];
    if (i < 31){
      const float* np = rowp + (size_t)B_*H_;
#pragma unroll
      for (int k = 0; k < 4; ++k)
        *reinterpret_cast<float4*>(nv[k]) = *reinterpret_cast<const float4*>(np + k*256 + lane*4);
    }
    float p = 0.f;
#pragma unroll
    for (int k = 0; k < 4; ++k)
#pragma unroll
      for (int j = 0; j < 4; ++j) p = fmaf(rv[k][j], qv[k][j], p);
#pragma unroll
    for (int off = 1; off < 64; off <<= 1) p += __shfl_xor(p, off, 64);
    float e = p + tb;
    if (lane == 0) e_out[(size_t)b*S_ + s0 + i] = e;
    float mn = fmaxf(m, e);
    float sc = expf(m - mn);     // 0 on first iter (m=-inf)
    float w  = expf(e - mn);
#pragma unroll
    for (int k = 0; k < 4; ++k)
#pragma unroll
      for (int j = 0; j < 4; ++j) ctx[k][j] = fmaf(w, rv[k][j], ctx[k][j]*sc);
    m = mn;
    rowp += (size_t)B_*H_;
    if (i < 31){
#pragma unroll
      for (int k = 0; k < 4; ++k)
#pragma unroll
        for (int j = 0; j < 4; ++j) rv[k][j] = nv[k][j];
    }
  }
  int pidx = b*16 + chunk*4 + wave;
  float* cp = ctxp + (size_t)pidx*H_;
#pragma unroll
  for (int k = 0; k < 4; ++k)
    *reinterpret_cast<float4*>(cp + k*256 + lane*4) = *reinterpret_cast<const float4*>(ctx[k]);
  if (lane == 0) mw[pidx] = m;
}

// ---------------- K5: softmax (attn_weights out) + ctx combine --------
__global__ __launch_bounds__(256) void softmax_combine(const float* __restrict__ e, const float* __restrict__ mw,
                                                       const float* __restrict__ ctxp, float* __restrict__ attn_out,
                                                       float* __restrict__ ctx){
  int b = blockIdx.x;
  int tid = threadIdx.x;
  __shared__ float red[4];
  __shared__ float Msh, Lsh;
  __shared__ float scs[16];
  float e0 = e[(size_t)b*S_ + tid];
  float e1 = e[(size_t)b*S_ + 256 + tid];
  float mx = fmaxf(e0, e1);
#pragma unroll
  for (int off = 1; off < 64; off <<= 1) mx = fmaxf(mx, __shfl_xor(mx, off, 64));
  if ((tid & 63) == 0) red[tid >> 6] = mx;
  __syncthreads();
  if (tid == 0) Msh = fmaxf(fmaxf(red[0], red[1]), fmaxf(red[2], red[3]));
  __syncthreads();
  float M = Msh;
  float w0 = expf(e0 - M), w1 = expf(e1 - M);
  float ls = w0 + w1;
#pragma unroll
  for (int off = 1; off < 64; off <<= 1) ls += __shfl_xor(ls, off, 64);
  if ((tid & 63) == 0) red[tid >> 6] = ls;
  __syncthreads();
  if (tid == 0) Lsh = red[0] + red[1] + red[2] + red[3];
  __syncthreads();
  float Linv = 1.0f / Lsh;
  attn_out[(size_t)b*S_ + tid]       = w0 * Linv;
  attn_out[(size_t)b*S_ + 256 + tid] = w1 * Linv;
  if (tid < 16) scs[tid] = expf(mw[b*16 + tid] - M) * Linv;
  __syncthreads();
#pragma unroll
  for (int it = 0; it < 4; ++it){
    int d = it*256 + tid;
    float acc = 0.f;
#pragma unroll
    for (int j = 0; j < 16; ++j) acc = fmaf(scs[j], ctxp[(size_t)(b*16 + j)*H_ + d], acc);
    ctx[(size_t)b*H_ + d] = acc;
  }
}

// ======================================================================
extern "C" void kernel_launch(void* const* d_in, const int* in_sizes, int n_in,
                              void* d_out, int out_size, void* d_ws, size_t ws_size,
                              hipStream_t stream){
  (void)in_sizes; (void)n_in; (void)out_size; (void)ws_size;
  const float* input_seq = (const float*)d_in[0];
  const float* last_hid  = (const float*)d_in[1];
  const float* enc       = (const float*)d_in[2];
  const float* W_ih      = (const float*)d_in[3];
  const float* b_ih      = (const float*)d_in[4];
  const float* W_hh      = (const float*)d_in[5];
  const float* b_hh      = (const float*)d_in[6];
  const float* W_attn    = (const float*)d_in[7];
  const float* b_attn    = (const float*)d_in[8];
  const float* W_concat  = (const float*)d_in[9];
  const float* b_concat  = (const float*)d_in[10];
  const float* W_out     = (const float*)d_in[11];
  const float* b_out     = (const float*)d_in[12];

  float* out = (float*)d_out;           // [0,131072) output | [131072,262144) hidden | [262144,327680) attn_w
  float* ws  = (float*)d_ws;

  // ws layout (floats). Region A is G (K1/K2) then reused as ctxp (K4+).
  float* G    = ws;                     // 128*6144 = 786432   (within region A)
  float* ctxp = ws;                     // 128*16*1024 = 2097152 (region A, reused after K2)
  float* rnn  = ws + 2097152;           // 131072
  float* q    = ws + 2228224;           // 131072
  float* t    = ws + 2359296;           // 128
  float* e    = ws + 2359424;           // 65536
  float* mw   = ws + 2424960;           // 2048
  float* ctx  = ws + 2427008;           // 131072
  float* co   = ws + 2558080;           // 131072  -> total 2689152 floats = 10.8 MB

  dim3 blk(256);
  // K1: gi|gh
  gru_gemm<<<384, blk, 0, stream>>>(input_seq, last_hid, W_ih, W_hh, b_ih, b_hh, G);
  // K2: gates -> rnn_output, hidden out, t[b] (fused)
  gru_gates<<<128, dim3(1024), 0, stream>>>(G, last_hid, b_attn, rnn, out + 131072, t);
  // K3: q = rnn @ W_attn  (W k-major)
  gemm_tile<1024, false, 0, false><<<64, blk, 0, stream>>>(rnn, nullptr, W_attn, nullptr, q);
  // K4: one-pass attention over enc
  attn_pass<<<dim3(128, 4), blk, 0, stream>>>(enc, q, t, e, ctxp, mw);
  // K5: softmax -> attn_weights out + ctx combine
  softmax_combine<<<128, blk, 0, stream>>>(e, mw, ctxp, out + 262144, ctx);
  // K7: concat head: tanh([rnn|ctx] @ W_concat^T + b_concat)
  gemm_tile<2048, true, 1, true><<<64, blk, 0, stream>>>(rnn, ctx, W_concat, b_concat, co);
  // K8: out head: sigmoid(co @ W_out^T + b_out) -> output
  gemm_tile<1024, true, 2, false><<<64, blk, 0, stream>>>(co, nullptr, W_out, b_out, out);
}

// Round 8
// 546.531 us; speedup vs baseline: 1.2723x; 1.2723x over previous
//
#include <hip/hip_runtime.h>
#include <cstddef>

// Problem constants
#define B_ 128
#define H_ 1024
#define S_ 512

// ======================================================================
// Shared skinny-GEMM tile machinery: M=128 (all batch), BN=16, KC=64.
// A staged transposed+XOR-swizzled in LDS: As[k][b ^ xc(k)] = A[b][k0+k],
// xc(k) = ((k>>2)&7)<<2  -> conflict-free b128 on both store and load.
// W staged as Ws[n][k] (16x68, pad for banks).
// Thread (tb=tid&31, tn=tid>>5) computes 4 consecutive b x 2 n outputs.
// Split-K across blockIdx.y: partials summed by a combine kernel
// (64-block grids only covered 25% of the 256 CUs; split-K x4 fixes that).
// ======================================================================

__device__ __forceinline__ void stage_A128(float* As, const float* __restrict__ A, int k0, int tid){
  int c4 = tid & 15, rowg = tid >> 4;
#pragma unroll
  for (int p = 0; p < 8; ++p){
    int row = p*16 + rowg;
    const float4 v = *reinterpret_cast<const float4*>(A + (size_t)row*H_ + k0 + c4*4);
    int colx = row ^ ((c4 & 7) << 2);
    float* d0 = As + (c4*4)*132 + colx;
    d0[0]     = v.x;
    d0[132]   = v.y;
    d0[264]   = v.z;
    d0[396]   = v.w;
  }
}

// W row-major [N][ldw] (weight rows = output features, contiguous K)
__device__ __forceinline__ void stage_W_wt(float* Ws, const float* __restrict__ W, int n0, int k0, int ldw, int tid){
  int n = tid >> 4, c4 = tid & 15;
  const float4 v = *reinterpret_cast<const float4*>(W + (size_t)(n0+n)*ldw + k0 + c4*4);
  *reinterpret_cast<float4*>(Ws + n*68 + c4*4) = v;
}

// W k-major [K][ldw] (q = rnn @ W_attn case): Ws[n][k] = W[k0+k][n0+n]
__device__ __forceinline__ void stage_W_wn(float* Ws, const float* __restrict__ W, int n0, int k0, int ldw, int tid){
  int k = tid >> 2, c4 = tid & 3;
  const float4 v = *reinterpret_cast<const float4*>(W + (size_t)(k0+k)*ldw + n0 + c4*4);
  Ws[(c4*4+0)*68 + k] = v.x;
  Ws[(c4*4+1)*68 + k] = v.y;
  Ws[(c4*4+2)*68 + k] = v.z;
  Ws[(c4*4+3)*68 + k] = v.w;
}

__device__ __forceinline__ void compute_chunk(const float* As, const float* Ws, int tb, int tn, float acc[4][2]){
#pragma unroll
  for (int kk = 0; kk < 64; kk += 4){
    int col = (4*tb) ^ (((kk >> 2) & 7) << 2);
    float av[4][4];
#pragma unroll
    for (int k = 0; k < 4; ++k)
      *reinterpret_cast<float4*>(av[k]) = *reinterpret_cast<const float4*>(As + (kk+k)*132 + col);
    float w0[4], w1[4];
    *reinterpret_cast<float4*>(w0) = *reinterpret_cast<const float4*>(Ws + (tn*2+0)*68 + kk);
    *reinterpret_cast<float4*>(w1) = *reinterpret_cast<const float4*>(Ws + (tn*2+1)*68 + kk);
#pragma unroll
    for (int k = 0; k < 4; ++k){
#pragma unroll
      for (int i = 0; i < 4; ++i){
        acc[i][0] = fmaf(av[k][i], w0[k], acc[i][0]);
        acc[i][1] = fmaf(av[k][i], w1[k], acc[i][1]);
      }
    }
  }
}

// ---------------- K1: gi|gh GEMM partials -> G[2][128][6144] ----------
// cols 0..3071 = input_seq @ W_ih^T ; 3072..6143 = h @ W_hh^T (no bias;
// bias folded into gru_gates). blockIdx.y = K-half (split-K x2).
__global__ __launch_bounds__(256) void gru_gemm(const float* __restrict__ Ain, const float* __restrict__ Ah,
                                                const float* __restrict__ Wih, const float* __restrict__ Whh,
                                                float* __restrict__ G){
  __shared__ float As[64*132];
  __shared__ float Ws[16*68];
  int tid = threadIdx.x;
  int n0g = blockIdx.x * 16;
  int kbase = blockIdx.y * 512;
  const float* A; const float* W; int n0;
  if (n0g < 3072){ A = Ain; W = Wih; n0 = n0g; }
  else           { A = Ah;  W = Whh; n0 = n0g - 3072; }
  int tb = tid & 31, tn = tid >> 5;
  float acc[4][2] = {{0.f,0.f},{0.f,0.f},{0.f,0.f},{0.f,0.f}};
  for (int kq = 0; kq < 512; kq += 64){
    int k0 = kbase + kq;
    __syncthreads();
    stage_A128(As, A, k0, tid);
    stage_W_wt(Ws, W, n0, k0, H_, tid);
    __syncthreads();
    compute_chunk(As, Ws, tb, tn, acc);
  }
  float* Gp = G + (size_t)blockIdx.y * 786432;
#pragma unroll
  for (int i = 0; i < 4; ++i){
    int b = tb*4 + i;
#pragma unroll
    for (int j = 0; j < 2; ++j){
      int n = tn*2 + j;
      Gp[(size_t)b*6144 + n0g + n] = acc[i][j];
    }
  }
}

// ---------------- generic split-K partial GEMM (K3 q, K7 concat, K8 out)
template<int KSUB, bool WT, bool ASPLIT>
__global__ __launch_bounds__(256) void gemm_partial(const float* __restrict__ A1, const float* __restrict__ A2,
                                                    const float* __restrict__ W, int ldw,
                                                    float* __restrict__ partial){
  __shared__ float As[64*132];
  __shared__ float Ws[16*68];
  int tid = threadIdx.x;
  int n0 = blockIdx.x * 16;
  int kbase = blockIdx.y * KSUB;
  int tb = tid & 31, tn = tid >> 5;
  float acc[4][2] = {{0.f,0.f},{0.f,0.f},{0.f,0.f},{0.f,0.f}};
  for (int kq = 0; kq < KSUB; kq += 64){
    int k0 = kbase + kq;
    const float* A = A1; int keff = k0;
    if (ASPLIT && k0 >= 1024){ A = A2; keff = k0 - 1024; }
    __syncthreads();
    stage_A128(As, A, keff, tid);
    if (WT) stage_W_wt(Ws, W, n0, k0, ldw, tid);
    else    stage_W_wn(Ws, W, n0, k0, ldw, tid);
    __syncthreads();
    compute_chunk(As, Ws, tb, tn, acc);
  }
  float* P = partial + (size_t)blockIdx.y * (B_*H_);
#pragma unroll
  for (int i = 0; i < 4; ++i){
    int b = tb*4 + i;
#pragma unroll
    for (int j = 0; j < 2; ++j){
      int n = tn*2 + j;
      P[(size_t)b*1024 + n0 + n] = acc[i][j];
    }
  }
}

// ---------------- combine: sum NP partials + bias + activation --------
template<int ACT, int NP>
__global__ __launch_bounds__(256) void combine(const float* __restrict__ partial, const float* __restrict__ bias,
                                               float* __restrict__ C){
  int idx = blockIdx.x*256 + threadIdx.x;   // 0..131071
  float v = 0.f;
#pragma unroll
  for (int j = 0; j < NP; ++j) v += partial[(size_t)j*(B_*H_) + idx];
  if (bias) v += bias[idx & 1023];
  if (ACT == 1) v = tanhf(v);
  if (ACT == 2) v = 1.f/(1.f + expf(-v));
  C[idx] = v;
}

// ---------------- K2: GRU gates (sums K1 halves + biases) -> rnn, t[b]
__global__ __launch_bounds__(1024) void gru_gates(const float* __restrict__ G, const float* __restrict__ h,
                                                  const float* __restrict__ bih, const float* __restrict__ bhh,
                                                  const float* __restrict__ ba,
                                                  float* __restrict__ rnn, float* __restrict__ hid_out,
                                                  float* __restrict__ t){
  int b = blockIdx.x, c = threadIdx.x;
  __shared__ float red[16];
  const float* g0 = G + (size_t)b*6144;
  const float* g1 = G + 786432 + (size_t)b*6144;
  float ir  = g0[c]      + g1[c]      + bih[c];
  float iz  = g0[c+1024] + g1[c+1024] + bih[c+1024];
  float in_ = g0[c+2048] + g1[c+2048] + bih[c+2048];
  float hr  = g0[c+3072] + g1[c+3072] + bhh[c];
  float hz  = g0[c+4096] + g1[c+4096] + bhh[c+1024];
  float hn  = g0[c+5120] + g1[c+5120] + bhh[c+2048];
  float r = 1.f/(1.f + expf(-(ir + hr)));
  float z = 1.f/(1.f + expf(-(iz + hz)));
  float n = tanhf(in_ + r*hn);
  float hv = h[(size_t)b*H_ + c];
  float o = (1.f - z)*n + z*hv;
  rnn[(size_t)b*H_ + c] = o;
  hid_out[(size_t)b*H_ + c] = o;
  // block-reduce o * b_attn[c] -> t[b]
  float s = o * ba[c];
#pragma unroll
  for (int off = 1; off < 64; off <<= 1) s += __shfl_xor(s, off, 64);
  if ((c & 63) == 0) red[c >> 6] = s;
  __syncthreads();
  if (c == 0){
    float acc = 0.f;
#pragma unroll
    for (int j = 0; j < 16; ++j) acc += red[j];
    t[b] = acc;
  }
}

// ---------------- K4: one-pass flash attention over enc ---------------
// grid (128 b, 8 chunk) x 256 thr (4 waves) = 1024 blocks (16 waves/CU).
// Wave owns 16 s-rows of one b; partial (m, ctx[1024]) per (b,chunk,wave).
__global__ __launch_bounds__(256) void attn_pass(const float* __restrict__ enc, const float* __restrict__ q,
                                                 const float* __restrict__ t, float* __restrict__ e_out,
                                                 float* __restrict__ ctxp, float* __restrict__ mw){
  int b = blockIdx.x;
  int chunk = blockIdx.y;
  int wave = threadIdx.x >> 6;
  int lane = threadIdx.x & 63;
  int s0 = chunk*64 + wave*16;

  float qv[4][4];
#pragma unroll
  for (int k = 0; k < 4; ++k)
    *reinterpret_cast<float4*>(qv[k]) = *reinterpret_cast<const float4*>(q + (size_t)b*H_ + k*256 + lane*4);
  const float tb = t[b];

  float m = -INFINITY;
  float ctx[4][4] = {{0}};
  const float* rowp = enc + ((size_t)s0 * B_ + b) * H_;
  float rv[4][4];
#pragma unroll
  for (int k = 0; k < 4; ++k)
    *reinterpret_cast<float4*>(rv[k]) = *reinterpret_cast<const float4*>(rowp + k*256 + lane*4);

  for (int i = 0; i < 16; ++i){
    float nv[4][4];
    if (i < 15){
      const float* np = rowp + (size_t)B_*H_;
#pragma unroll
      for (int k = 0; k < 4; ++k)
        *reinterpret_cast<float4*>(nv[k]) = *reinterpret_cast<const float4*>(np + k*256 + lane*4);
    }
    float p = 0.f;
#pragma unroll
    for (int k = 0; k < 4; ++k)
#pragma unroll
      for (int j = 0; j < 4; ++j) p = fmaf(rv[k][j], qv[k][j], p);
#pragma unroll
    for (int off = 1; off < 64; off <<= 1) p += __shfl_xor(p, off, 64);
    float e = p + tb;
    if (lane == 0) e_out[(size_t)b*S_ + s0 + i] = e;
    float mn = fmaxf(m, e);
    float sc = expf(m - mn);     // 0 on first iter (m=-inf)
    float w  = expf(e - mn);
#pragma unroll
    for (int k = 0; k < 4; ++k)
#pragma unroll
      for (int j = 0; j < 4; ++j) ctx[k][j] = fmaf(w, rv[k][j], ctx[k][j]*sc);
    m = mn;
    rowp += (size_t)B_*H_;
    if (i < 15){
#pragma unroll
      for (int k = 0; k < 4; ++k)
#pragma unroll
        for (int j = 0; j < 4; ++j) rv[k][j] = nv[k][j];
    }
  }
  int pidx = b*32 + chunk*4 + wave;
  float* cp = ctxp + (size_t)pidx*H_;
#pragma unroll
  for (int k = 0; k < 4; ++k)
    *reinterpret_cast<float4*>(cp + k*256 + lane*4) = *reinterpret_cast<const float4*>(ctx[k]);
  if (lane == 0) mw[pidx] = m;
}

// ---------------- K5: softmax (attn_weights out) + ctx combine --------
__global__ __launch_bounds__(256) void softmax_combine(const float* __restrict__ e, const float* __restrict__ mw,
                                                       const float* __restrict__ ctxp, float* __restrict__ attn_out,
                                                       float* __restrict__ ctx){
  int b = blockIdx.x;
  int tid = threadIdx.x;
  __shared__ float red[4];
  __shared__ float Msh, Lsh;
  __shared__ float scs[32];
  float e0 = e[(size_t)b*S_ + tid];
  float e1 = e[(size_t)b*S_ + 256 + tid];
  float mx = fmaxf(e0, e1);
#pragma unroll
  for (int off = 1; off < 64; off <<= 1) mx = fmaxf(mx, __shfl_xor(mx, off, 64));
  if ((tid & 63) == 0) red[tid >> 6] = mx;
  __syncthreads();
  if (tid == 0) Msh = fmaxf(fmaxf(red[0], red[1]), fmaxf(red[2], red[3]));
  __syncthreads();
  float M = Msh;
  float w0 = expf(e0 - M), w1 = expf(e1 - M);
  float ls = w0 + w1;
#pragma unroll
  for (int off = 1; off < 64; off <<= 1) ls += __shfl_xor(ls, off, 64);
  if ((tid & 63) == 0) red[tid >> 6] = ls;
  __syncthreads();
  if (tid == 0) Lsh = red[0] + red[1] + red[2] + red[3];
  __syncthreads();
  float Linv = 1.0f / Lsh;
  attn_out[(size_t)b*S_ + tid]       = w0 * Linv;
  attn_out[(size_t)b*S_ + 256 + tid] = w1 * Linv;
  if (tid < 32) scs[tid] = expf(mw[b*32 + tid] - M) * Linv;
  __syncthreads();
#pragma unroll
  for (int it = 0; it < 4; ++it){
    int d = it*256 + tid;
    float acc = 0.f;
#pragma unroll
    for (int j = 0; j < 32; ++j) acc = fmaf(scs[j], ctxp[(size_t)(b*32 + j)*H_ + d], acc);
    ctx[(size_t)b*H_ + d] = acc;
  }
}

// ======================================================================
extern "C" void kernel_launch(void* const* d_in, const int* in_sizes, int n_in,
                              void* d_out, int out_size, void* d_ws, size_t ws_size,
                              hipStream_t stream){
  (void)in_sizes; (void)n_in; (void)out_size; (void)ws_size;
  const float* input_seq = (const float*)d_in[0];
  const float* last_hid  = (const float*)d_in[1];
  const float* enc       = (const float*)d_in[2];
  const float* W_ih      = (const float*)d_in[3];
  const float* b_ih      = (const float*)d_in[4];
  const float* W_hh      = (const float*)d_in[5];
  const float* b_hh      = (const float*)d_in[6];
  const float* W_attn    = (const float*)d_in[7];
  const float* b_attn    = (const float*)d_in[8];
  const float* W_concat  = (const float*)d_in[9];
  const float* b_concat  = (const float*)d_in[10];
  const float* W_out     = (const float*)d_in[11];
  const float* b_out     = (const float*)d_in[12];

  float* out = (float*)d_out;           // [0,131072) output | [131072,262144) hidden | [262144,327680) attn_w
  float* ws  = (float*)d_ws;

  // ws layout (floats), all 16B-aligned:
  float* G    = ws;                     // 2 x 786432 = 1572864 (K1 split-K partials)
  float* rnn  = ws + 1572864;           // 131072
  float* q    = ws + 1703936;           // 131072
  float* t    = ws + 1835008;           // 128
  float* e    = ws + 1835136;           // 65536
  float* mw   = ws + 1900672;           // 4096
  float* ctx  = ws + 1904768;           // 131072
  float* co   = ws + 2035840;           // 131072
  float* part = ws + 2166912;           // 4 x 131072 = 524288 (split-K partials, reused)
  float* ctxp = ws + 2691200;           // 128*32*1024 = 4194304  -> total 27.5 MB

  dim3 blk(256);
  // K1: gi|gh partials (split-K x2, 768 blocks)
  gru_gemm<<<dim3(384,2), blk, 0, stream>>>(input_seq, last_hid, W_ih, W_hh, G);
  // K2: gates (sums halves + biases) -> rnn, hidden out, t[b]
  gru_gates<<<128, dim3(1024), 0, stream>>>(G, last_hid, b_ih, b_hh, b_attn, rnn, out + 131072, t);
  // K3: q = rnn @ W_attn  (W k-major, split-K x4 + combine)
  gemm_partial<256, false, false><<<dim3(64,4), blk, 0, stream>>>(rnn, nullptr, W_attn, 1024, part);
  combine<0, 4><<<512, blk, 0, stream>>>(part, nullptr, q);
  // K4: one-pass attention over enc (1024 blocks)
  attn_pass<<<dim3(128, 8), blk, 0, stream>>>(enc, q, t, e, ctxp, mw);
  // K5: softmax -> attn_weights out + ctx combine
  softmax_combine<<<128, blk, 0, stream>>>(e, mw, ctxp, out + 262144, ctx);
  // K7: concat head partials: [rnn|ctx] @ W_concat^T (split-K x4), tanh in combine
  gemm_partial<512, true, true><<<dim3(64,4), blk, 0, stream>>>(rnn, ctx, W_concat, 2048, part);
  combine<1, 4><<<512, blk, 0, stream>>>(part, b_concat, co);
  // K8: out head partials: co @ W_out^T (split-K x4), sigmoid in combine
  gemm_partial<256, true, false><<<dim3(64,4), blk, 0, stream>>>(co, nullptr, W_out, 1024, part);
  combine<2, 4><<<512, blk, 0, stream>>>(part, b_out, out);
}

// Round 9
// 532.731 us; speedup vs baseline: 1.3053x; 1.0259x over previous
//
#include <hip/hip_runtime.h>
#include <cstddef>

// Problem constants
#define B_ 128
#define H_ 1024
#define S_ 512

// ======================================================================
// GEMM v2: M=128 (all batch), BN=16, KC=64/chunk, 256 thr = 4 waves.
// Intra-block K-split: wave w handles k in [w*16, w*16+16) of each chunk,
// accumulating its own split-K plane (plane = blockIdx.y*4 + w). A combine
// kernel (or consumer) sums the 16 planes. Per k-step each thread does
// 3 ds_read_b128 for 32 FMAs (old scheme: 6 per 32 -> 4x less LDS/FMA).
// A transposed in LDS: As[k][bpad(b)], bpad(b)=b+((b>>4)<<2), ld=156:
// 16 distinct 16B reads/instr land 2-way per bank quad = 2-phase minimum.
// W as Wt[k][n], ld=20: 4 distinct 16B + 16-way broadcast = 1 phase.
// ======================================================================

__device__ __forceinline__ int bpad(int b){ return b + ((b >> 4) << 2); }

#define LDA 156
#define LDW 20

__device__ __forceinline__ void stage_A2(float* As, const float* __restrict__ A, int k0, int tid){
  int c4 = tid & 15, rowg = tid >> 4;
#pragma unroll
  for (int p = 0; p < 8; ++p){
    int row = p*16 + rowg;
    const float4 v = *reinterpret_cast<const float4*>(A + (size_t)row*H_ + k0 + c4*4);
    float* d = As + (c4*4)*LDA + bpad(row);
    d[0]     = v.x;
    d[LDA]   = v.y;
    d[2*LDA] = v.z;
    d[3*LDA] = v.w;
  }
}

// W row-major [N][ldw] (weight rows = output features, contiguous K)
__device__ __forceinline__ void stage_Wt_wt(float* Wt, const float* __restrict__ W, int n0, int k0, int ldw, int tid){
  int n = tid >> 4, c4 = tid & 15;
  const float4 v = *reinterpret_cast<const float4*>(W + (size_t)(n0+n)*ldw + k0 + c4*4);
  float* d = Wt + (c4*4)*LDW + n;
  d[0]     = v.x;
  d[LDW]   = v.y;
  d[2*LDW] = v.z;
  d[3*LDW] = v.w;
}

// W k-major [K][ldw] (q = rnn @ W_attn case): Wt[k][n] = W[k0+k][n0+n]
__device__ __forceinline__ void stage_Wt_wn(float* Wt, const float* __restrict__ W, int n0, int k0, int ldw, int tid){
  int k = tid >> 2, c4 = tid & 3;
  const float4 v = *reinterpret_cast<const float4*>(W + (size_t)(k0+k)*ldw + n0 + c4*4);
  *reinterpret_cast<float4*>(Wt + k*LDW + c4*4) = v;
}

__device__ __forceinline__ void compute_chunk2(const float* As, const float* Wt, int wave, int bp0, int ng,
                                               float acc[8][4]){
#pragma unroll
  for (int kk = 0; kk < 16; ++kk){
    int k = wave*16 + kk;
    const float* r = As + k*LDA;
    float a[8], w[4];
    *reinterpret_cast<float4*>(&a[0]) = *reinterpret_cast<const float4*>(r + bp0);
    *reinterpret_cast<float4*>(&a[4]) = *reinterpret_cast<const float4*>(r + bp0 + 4);
    *reinterpret_cast<float4*>(&w[0]) = *reinterpret_cast<const float4*>(Wt + k*LDW + ng*4);
#pragma unroll
    for (int i = 0; i < 8; ++i)
#pragma unroll
      for (int j = 0; j < 4; ++j)
        acc[i][j] = fmaf(a[i], w[j], acc[i][j]);
  }
}

// ---------------- K1: gi|gh GEMM partials -> G[8][128][6144] ----------
// cols 0..3071 = input_seq @ W_ih^T ; 3072..6143 = h @ W_hh^T (no bias;
// bias folded into gru_gates). plane = blockIdx.y*4 + wave (8 planes).
__global__ __launch_bounds__(256) void gru_gemm(const float* __restrict__ Ain, const float* __restrict__ Ah,
                                                const float* __restrict__ Wih, const float* __restrict__ Whh,
                                                float* __restrict__ G){
  __shared__ float As[64*LDA];
  __shared__ float Wt[64*LDW];
  int tid = threadIdx.x;
  int n0g = blockIdx.x * 16;
  int kbase = blockIdx.y * 512;
  const float* A; const float* W; int n0;
  if (n0g < 3072){ A = Ain; W = Wih; n0 = n0g; }
  else           { A = Ah;  W = Whh; n0 = n0g - 3072; }
  int wave = tid >> 6, lane = tid & 63;
  int bg = lane & 15, ng = lane >> 4;
  int b0 = bg*8, bp0 = bpad(b0);
  float acc[8][4] = {};
  for (int kq = 0; kq < 512; kq += 64){
    int k0 = kbase + kq;
    __syncthreads();
    stage_A2(As, A, k0, tid);
    stage_Wt_wt(Wt, W, n0, k0, H_, tid);
    __syncthreads();
    compute_chunk2(As, Wt, wave, bp0, ng, acc);
  }
  float* Gp = G + (size_t)(blockIdx.y*4 + wave) * 786432;
#pragma unroll
  for (int i = 0; i < 8; ++i){
    float4 v = make_float4(acc[i][0], acc[i][1], acc[i][2], acc[i][3]);
    *reinterpret_cast<float4*>(Gp + (size_t)(b0+i)*6144 + n0g + ng*4) = v;
  }
}

// ---------------- generic split-K partial GEMM (K3 q, K7 concat, K8 out)
// 16 planes: plane = blockIdx.y*4 + wave.
template<int KSUB, bool WT, bool ASPLIT>
__global__ __launch_bounds__(256) void gemm_partial(const float* __restrict__ A1, const float* __restrict__ A2,
                                                    const float* __restrict__ W, int ldw,
                                                    float* __restrict__ partial){
  __shared__ float As[64*LDA];
  __shared__ float Wt[64*LDW];
  int tid = threadIdx.x;
  int n0 = blockIdx.x * 16;
  int kbase = blockIdx.y * KSUB;
  int wave = tid >> 6, lane = tid & 63;
  int bg = lane & 15, ng = lane >> 4;
  int b0 = bg*8, bp0 = bpad(b0);
  float acc[8][4] = {};
  for (int kq = 0; kq < KSUB; kq += 64){
    int k0 = kbase + kq;
    const float* A = A1; int keff = k0;
    if (ASPLIT && k0 >= 1024){ A = A2; keff = k0 - 1024; }
    __syncthreads();
    stage_A2(As, A, keff, tid);
    if (WT) stage_Wt_wt(Wt, W, n0, k0, ldw, tid);
    else    stage_Wt_wn(Wt, W, n0, k0, ldw, tid);
    __syncthreads();
    compute_chunk2(As, Wt, wave, bp0, ng, acc);
  }
  float* P = partial + (size_t)(blockIdx.y*4 + wave) * (B_*H_);
#pragma unroll
  for (int i = 0; i < 8; ++i){
    float4 v = make_float4(acc[i][0], acc[i][1], acc[i][2], acc[i][3]);
    *reinterpret_cast<float4*>(P + (size_t)(b0+i)*1024 + n0 + ng*4) = v;
  }
}

// ---------------- combine: sum 16 partial planes + bias + activation --
template<int ACT>
__global__ __launch_bounds__(256) void combine(const float* __restrict__ partial, const float* __restrict__ bias,
                                               float* __restrict__ C){
  int idx = blockIdx.x*256 + threadIdx.x;   // 0..131071
  float v = 0.f;
#pragma unroll
  for (int j = 0; j < 16; ++j) v += partial[(size_t)j*(B_*H_) + idx];
  if (bias) v += bias[idx & 1023];
  if (ACT == 1) v = tanhf(v);
  if (ACT == 2) v = 1.f/(1.f + expf(-v));
  C[idx] = v;
}

// ---------------- K2: GRU gates (sums 8 K1 planes + biases) -> rnn, t[b]
__global__ __launch_bounds__(1024) void gru_gates(const float* __restrict__ G, const float* __restrict__ h,
                                                  const float* __restrict__ bih, const float* __restrict__ bhh,
                                                  const float* __restrict__ ba,
                                                  float* __restrict__ rnn, float* __restrict__ hid_out,
                                                  float* __restrict__ t){
  int b = blockIdx.x, c = threadIdx.x;
  __shared__ float red[16];
  float ir = bih[c], iz = bih[c+1024], in_ = bih[c+2048];
  float hr = bhh[c], hz = bhh[c+1024], hn  = bhh[c+2048];
#pragma unroll
  for (int p = 0; p < 8; ++p){
    const float* g = G + (size_t)p*786432 + (size_t)b*6144;
    ir  += g[c];      iz += g[c+1024]; in_ += g[c+2048];
    hr  += g[c+3072]; hz += g[c+4096]; hn  += g[c+5120];
  }
  float r = 1.f/(1.f + expf(-(ir + hr)));
  float z = 1.f/(1.f + expf(-(iz + hz)));
  float n = tanhf(in_ + r*hn);
  float hv = h[(size_t)b*H_ + c];
  float o = (1.f - z)*n + z*hv;
  rnn[(size_t)b*H_ + c] = o;
  hid_out[(size_t)b*H_ + c] = o;
  // block-reduce o * b_attn[c] -> t[b]
  float s = o * ba[c];
#pragma unroll
  for (int off = 1; off < 64; off <<= 1) s += __shfl_xor(s, off, 64);
  if ((c & 63) == 0) red[c >> 6] = s;
  __syncthreads();
  if (c == 0){
    float acc = 0.f;
#pragma unroll
    for (int j = 0; j < 16; ++j) acc += red[j];
    t[b] = acc;
  }
}

// ---------------- K4: one-pass flash attention over enc ---------------
// grid (128 b, 8 chunk) x 256 thr (4 waves). Wave owns 16 s-rows of one b.
// q summed inline from 16 K3 partial planes (saves a combine node).
__global__ __launch_bounds__(256) void attn_pass(const float* __restrict__ enc, const float* __restrict__ qpart,
                                                 const float* __restrict__ t, float* __restrict__ e_out,
                                                 float* __restrict__ ctxp, float* __restrict__ mw){
  int b = blockIdx.x;
  int chunk = blockIdx.y;
  int wave = threadIdx.x >> 6;
  int lane = threadIdx.x & 63;
  int s0 = chunk*64 + wave*16;

  float qv[4][4];
#pragma unroll
  for (int k = 0; k < 4; ++k){
    float4 s = make_float4(0.f,0.f,0.f,0.f);
#pragma unroll
    for (int p = 0; p < 16; ++p){
      const float4 v = *reinterpret_cast<const float4*>(qpart + (size_t)p*(B_*H_) + (size_t)b*H_ + k*256 + lane*4);
      s.x += v.x; s.y += v.y; s.z += v.z; s.w += v.w;
    }
    qv[k][0]=s.x; qv[k][1]=s.y; qv[k][2]=s.z; qv[k][3]=s.w;
  }
  const float tb = t[b];

  float m = -INFINITY;
  float ctx[4][4] = {{0}};
  const float* rowp = enc + ((size_t)s0 * B_ + b) * H_;
  float rv[4][4];
#pragma unroll
  for (int k = 0; k < 4; ++k)
    *reinterpret_cast<float4*>(rv[k]) = *reinterpret_cast<const float4*>(rowp + k*256 + lane*4);

  for (int i = 0; i < 16; ++i){
    float nv[4][4];
    if (i < 15){
      const float* np = rowp + (size_t)B_*H_;
#pragma unroll
      for (int k = 0; k < 4; ++k)
        *reinterpret_cast<float4*>(nv[k]) = *reinterpret_cast<const float4*>(np + k*256 + lane*4);
    }
    float p = 0.f;
#pragma unroll
    for (int k = 0; k < 4; ++k)
#pragma unroll
      for (int j = 0; j < 4; ++j) p = fmaf(rv[k][j], qv[k][j], p);
#pragma unroll
    for (int off = 1; off < 64; off <<= 1) p += __shfl_xor(p, off, 64);
    float e = p + tb;
    if (lane == 0) e_out[(size_t)b*S_ + s0 + i] = e;
    float mn = fmaxf(m, e);
    float sc = expf(m - mn);     // 0 on first iter (m=-inf)
    float w  = expf(e - mn);
#pragma unroll
    for (int k = 0; k < 4; ++k)
#pragma unroll
      for (int j = 0; j < 4; ++j) ctx[k][j] = fmaf(w, rv[k][j], ctx[k][j]*sc);
    m = mn;
    rowp += (size_t)B_*H_;
    if (i < 15){
#pragma unroll
      for (int k = 0; k < 4; ++k)
#pragma unroll
        for (int j = 0; j < 4; ++j) rv[k][j] = nv[k][j];
    }
  }
  int pidx = b*32 + chunk*4 + wave;
  float* cp = ctxp + (size_t)pidx*H_;
#pragma unroll
  for (int k = 0; k < 4; ++k)
    *reinterpret_cast<float4*>(cp + k*256 + lane*4) = *reinterpret_cast<const float4*>(ctx[k]);
  if (lane == 0) mw[pidx] = m;
}

// ---------------- K5: softmax (attn_weights out) + ctx combine --------
__global__ __launch_bounds__(256) void softmax_combine(const float* __restrict__ e, const float* __restrict__ mw,
                                                       const float* __restrict__ ctxp, float* __restrict__ attn_out,
                                                       float* __restrict__ ctx){
  int b = blockIdx.x;
  int tid = threadIdx.x;
  __shared__ float red[4];
  __shared__ float Msh, Lsh;
  __shared__ float scs[32];
  float e0 = e[(size_t)b*S_ + tid];
  float e1 = e[(size_t)b*S_ + 256 + tid];
  float mx = fmaxf(e0, e1);
#pragma unroll
  for (int off = 1; off < 64; off <<= 1) mx = fmaxf(mx, __shfl_xor(mx, off, 64));
  if ((tid & 63) == 0) red[tid >> 6] = mx;
  __syncthreads();
  if (tid == 0) Msh = fmaxf(fmaxf(red[0], red[1]), fmaxf(red[2], red[3]));
  __syncthreads();
  float M = Msh;
  float w0 = expf(e0 - M), w1 = expf(e1 - M);
  float ls = w0 + w1;
#pragma unroll
  for (int off = 1; off < 64; off <<= 1) ls += __shfl_xor(ls, off, 64);
  if ((tid & 63) == 0) red[tid >> 6] = ls;
  __syncthreads();
  if (tid == 0) Lsh = red[0] + red[1] + red[2] + red[3];
  __syncthreads();
  float Linv = 1.0f / Lsh;
  attn_out[(size_t)b*S_ + tid]       = w0 * Linv;
  attn_out[(size_t)b*S_ + 256 + tid] = w1 * Linv;
  if (tid < 32) scs[tid] = expf(mw[b*32 + tid] - M) * Linv;
  __syncthreads();
#pragma unroll
  for (int it = 0; it < 4; ++it){
    int d = it*256 + tid;
    float acc = 0.f;
#pragma unroll
    for (int j = 0; j < 32; ++j) acc = fmaf(scs[j], ctxp[(size_t)(b*32 + j)*H_ + d], acc);
    ctx[(size_t)b*H_ + d] = acc;
  }
}

// ======================================================================
extern "C" void kernel_launch(void* const* d_in, const int* in_sizes, int n_in,
                              void* d_out, int out_size, void* d_ws, size_t ws_size,
                              hipStream_t stream){
  (void)in_sizes; (void)n_in; (void)out_size; (void)ws_size;
  const float* input_seq = (const float*)d_in[0];
  const float* last_hid  = (const float*)d_in[1];
  const float* enc       = (const float*)d_in[2];
  const float* W_ih      = (const float*)d_in[3];
  const float* b_ih      = (const float*)d_in[4];
  const float* W_hh      = (const float*)d_in[5];
  const float* b_hh      = (const float*)d_in[6];
  const float* W_attn    = (const float*)d_in[7];
  const float* b_attn    = (const float*)d_in[8];
  const float* W_concat  = (const float*)d_in[9];
  const float* b_concat  = (const float*)d_in[10];
  const float* W_out     = (const float*)d_in[11];
  const float* b_out     = (const float*)d_in[12];

  float* out = (float*)d_out;           // [0,131072) output | [131072,262144) hidden | [262144,327680) attn_w
  float* ws  = (float*)d_ws;

  // ws layout (floats), all 16B-aligned:
  float* G     = ws;                    // 8 x 786432 = 6291456 (K1 split-K planes)
  float* rnn   = ws + 6291456;          // 131072
  float* t     = ws + 6422528;          // 128
  float* e     = ws + 6422656;          // 65536
  float* mw    = ws + 6488192;          // 4096
  float* ctx   = ws + 6492288;          // 131072
  float* co    = ws + 6623360;          // 131072
  float* qpart = ws + 6754432;          // 16 x 131072 = 2097152
  float* part  = ws + 8851584;          // 16 x 131072 = 2097152 (reused by K7, K8)
  float* ctxp  = ws + 10948736;         // 128*32*1024 = 4194304  -> total ~60.6 MB

  dim3 blk(256);
  // K1: gi|gh partials (grid-K x2, wave-K x4 -> 8 planes)
  gru_gemm<<<dim3(384,2), blk, 0, stream>>>(input_seq, last_hid, W_ih, W_hh, G);
  // K2: gates (sums 8 planes + biases) -> rnn, hidden out, t[b]
  gru_gates<<<128, dim3(1024), 0, stream>>>(G, last_hid, b_ih, b_hh, b_attn, rnn, out + 131072, t);
  // K3: q partials = rnn @ W_attn  (W k-major, 16 planes; summed in attn)
  gemm_partial<256, false, false><<<dim3(64,4), blk, 0, stream>>>(rnn, nullptr, W_attn, 1024, qpart);
  // K4: one-pass attention over enc (1024 blocks), q summed inline
  attn_pass<<<dim3(128, 8), blk, 0, stream>>>(enc, qpart, t, e, ctxp, mw);
  // K5: softmax -> attn_weights out + ctx combine
  softmax_combine<<<128, blk, 0, stream>>>(e, mw, ctxp, out + 262144, ctx);
  // K7: concat head partials: [rnn|ctx] @ W_concat^T (16 planes), tanh in combine
  gemm_partial<512, true, true><<<dim3(64,4), blk, 0, stream>>>(rnn, ctx, W_concat, 2048, part);
  combine<1><<<512, blk, 0, stream>>>(part, b_concat, co);
  // K8: out head partials: co @ W_out^T (16 planes), sigmoid in combine
  gemm_partial<256, true, false><<<dim3(64,4), blk, 0, stream>>>(co, nullptr, W_out, 1024, part);
  combine<2><<<512, blk, 0, stream>>>(part, b_out, out);
}